// Round 1
// baseline (1479.959 us; speedup 1.0000x reference)
//
#include <hip/hip_runtime.h>
#include <math.h>

#define T_ 4
#define B_ 16
#define C_ 384
#define N_ 1024
#define CN_ (C_ * N_)      // 393216
#define BCN_ (B_ * CN_)    // 6291456
#define TBCN_ (T_ * BCN_)  // 25165824
#define HEADS_ 8
#define DH_ 48
#define EPS_ 1e-5f

// ---------------------------------------------------------------------------
// K1: shortcut LIF on x -> xs (binary spikes stored as fp32)
// v = v + (x - v)/2 ; s = (v - 1 >= 0) ; v *= (1 - s)   [exact elementwise ops]
// ---------------------------------------------------------------------------
__global__ __launch_bounds__(256) void lif_x_kernel(const float* __restrict__ x,
                                                    float* __restrict__ xs) {
    int idx = blockIdx.x * 256 + threadIdx.x;  // over BCN_
    float v = 0.f;
#pragma unroll
    for (int t = 0; t < T_; ++t) {
        float xt = x[(size_t)t * BCN_ + idx];
        v = v + (xt - v) * 0.5f;
        float s = (v - 1.0f >= 0.f) ? 1.f : 0.f;
        xs[(size_t)t * BCN_ + idx] = s;
        v = v * (1.f - s);
    }
}

// ---------------------------------------------------------------------------
// K2: fp32 GEMM  Y[tb, m, n] = sum_c W[m,c] * X[tb, c, n]
// tile: 128 (m) x 64 (n), K-chunks of 32, sequential-k accumulation.
// If pb != nullptr: proj epilogue  out = (acc + pb[m] - mean[m])*inv[m] + beta[m] + ident
// ---------------------------------------------------------------------------
__global__ __launch_bounds__(256) void gemm_kernel(
        const float* __restrict__ X, const float* __restrict__ Wm,
        float* __restrict__ Y,
        const float* __restrict__ pb, const float* __restrict__ pgamma,
        const float* __restrict__ pbeta, const float* __restrict__ pmean,
        const float* __restrict__ pvar, const float* __restrict__ ident) {
    __shared__ float Xs[32][64];    // [k][n]
    __shared__ float Ws[32][128];   // [k][m]
    const int tb = blockIdx.z;
    const int n0 = blockIdx.x * 64;
    const int m0 = blockIdx.y * 128;
    const float* Xb = X + (size_t)tb * CN_;
    const int tid = threadIdx.x;
    const int tx = tid & 15;   // n group: 4 cols
    const int ty = tid >> 4;   // m group: 8 rows

    float acc[8][4];
#pragma unroll
    for (int i = 0; i < 8; ++i)
#pragma unroll
        for (int j = 0; j < 4; ++j) acc[i][j] = 0.f;

    for (int c0 = 0; c0 < C_; c0 += 32) {
        // stage X tile: 32 rows x 64 cols = 512 float4, 2 per thread
#pragma unroll
        for (int l = 0; l < 2; ++l) {
            int j = tid + l * 256;
            int row = j >> 4, col = (j & 15) << 2;
            float4 t4 = *(const float4*)&Xb[(size_t)(c0 + row) * N_ + n0 + col];
            *(float4*)&Xs[row][col] = t4;
        }
        // stage W tile transposed: 128 rows(m) x 32 cols(k) = 1024 float4, 4/thread
#pragma unroll
        for (int l = 0; l < 4; ++l) {
            int j = tid + l * 256;
            int row = j >> 3, colf = j & 7;
            float4 t4 = *(const float4*)&Wm[(size_t)(m0 + row) * C_ + c0 + (colf << 2)];
            Ws[(colf << 2) + 0][row] = t4.x;
            Ws[(colf << 2) + 1][row] = t4.y;
            Ws[(colf << 2) + 2][row] = t4.z;
            Ws[(colf << 2) + 3][row] = t4.w;
        }
        __syncthreads();
#pragma unroll
        for (int kk = 0; kk < 32; ++kk) {
            float4 xv = *(const float4*)&Xs[kk][tx << 2];
            float4 wa = *(const float4*)&Ws[kk][ty << 3];
            float4 wb = *(const float4*)&Ws[kk][(ty << 3) + 4];
            float wv[8] = {wa.x, wa.y, wa.z, wa.w, wb.x, wb.y, wb.z, wb.w};
            float xq[4] = {xv.x, xv.y, xv.z, xv.w};
#pragma unroll
            for (int i = 0; i < 8; ++i)
#pragma unroll
                for (int j = 0; j < 4; ++j) acc[i][j] += wv[i] * xq[j];
        }
        __syncthreads();
    }

    float* Yb = Y + (size_t)tb * CN_;
    if (pb == nullptr) {
#pragma unroll
        for (int i = 0; i < 8; ++i) {
            int m = m0 + (ty << 3) + i;
            float4 o;
            o.x = acc[i][0]; o.y = acc[i][1]; o.z = acc[i][2]; o.w = acc[i][3];
            *(float4*)&Yb[(size_t)m * N_ + n0 + (tx << 2)] = o;
        }
    } else {
        const float* xb = ident + (size_t)tb * CN_;
#pragma unroll
        for (int i = 0; i < 8; ++i) {
            int m = m0 + (ty << 3) + i;
            float inv = pgamma[m] / sqrtf(pvar[m] + EPS_);
            float bi = pb[m], mu = pmean[m], be = pbeta[m];
            size_t off = (size_t)m * N_ + n0 + (tx << 2);
            float4 idv = *(const float4*)&xb[off];
            float4 o;
            o.x = (acc[i][0] + bi - mu) * inv + be + idv.x;
            o.y = (acc[i][1] + bi - mu) * inv + be + idv.y;
            o.z = (acc[i][2] + bi - mu) * inv + be + idv.z;
            o.w = (acc[i][3] + bi - mu) * inv + be + idv.w;
            *(float4*)&Yb[off] = o;
        }
    }
}

// ---------------------------------------------------------------------------
// K3: BN + LIF over T, in-place on y (writes binary spikes as fp32)
// ---------------------------------------------------------------------------
__global__ __launch_bounds__(256) void branch_lif_kernel(
        float* __restrict__ y, const float* __restrict__ gamma,
        const float* __restrict__ beta, const float* __restrict__ mean,
        const float* __restrict__ var) {
    int idx = blockIdx.x * 256 + threadIdx.x;  // over BCN_
    int c = (idx >> 10) % C_;                  // idx / N_ % C_
    float inv = gamma[c] / sqrtf(var[c] + EPS_);
    float mu = mean[c], be = beta[c];
    float v = 0.f;
#pragma unroll
    for (int t = 0; t < T_; ++t) {
        float pre = (y[(size_t)t * BCN_ + idx] - mu) * inv + be;
        v = v + (pre - v) * 0.5f;
        float s = (v - 1.0f >= 0.f) ? 1.f : 0.f;
        y[(size_t)t * BCN_ + idx] = s;
        v = v * (1.f - s);
    }
}

// ---------------------------------------------------------------------------
// K4: kv = LIF_t( sum_n k*v , v_th=0.5 )  — exact integer arithmetic.
// One block per (b,c); 256 threads reduce N=1024 for each t.
// kvsp layout: [t*B_*C_ + b*C_ + c]
// ---------------------------------------------------------------------------
__global__ __launch_bounds__(256) void kv_kernel(const float* __restrict__ k,
                                                 const float* __restrict__ v,
                                                 float* __restrict__ kvsp) {
    int bc = blockIdx.x;  // b*C_ + c
    __shared__ float red[256];
    __shared__ float cnt[T_];
#pragma unroll
    for (int t = 0; t < T_; ++t) {
        const float* kp = k + (size_t)t * BCN_ + (size_t)bc * N_;
        const float* vp = v + (size_t)t * BCN_ + (size_t)bc * N_;
        float p = 0.f;
        for (int n = threadIdx.x; n < N_; n += 256) p += kp[n] * vp[n];
        red[threadIdx.x] = p;
        __syncthreads();
        for (int s = 128; s > 0; s >>= 1) {
            if (threadIdx.x < s) red[threadIdx.x] += red[threadIdx.x + s];
            __syncthreads();
        }
        if (threadIdx.x == 0) cnt[t] = red[0];
        __syncthreads();
    }
    if (threadIdx.x == 0) {
        float u = 0.f;
#pragma unroll
        for (int t = 0; t < T_; ++t) {
            u = u + (cnt[t] - u) * 0.5f;
            float s = (u - 0.5f >= 0.f) ? 1.f : 0.f;
            kvsp[t * (B_ * C_) + bc] = s;
            u = u * (1.f - s);
        }
    }
}

// ---------------------------------------------------------------------------
// K5: transpose v spikes [tb][c][n] -> output1 head layout [tb][head][n][dd]
// grid: (n-tile 16, head 8, tb 64)
// ---------------------------------------------------------------------------
__global__ __launch_bounds__(256) void transpose_v_kernel(
        const float* __restrict__ vsp, float* __restrict__ out1) {
    __shared__ float tile[DH_][65];
    int tb = blockIdx.z, head = blockIdx.y, n0 = blockIdx.x * 64;
    const float* src = vsp + (size_t)tb * CN_ + (size_t)head * DH_ * N_ + n0;
    int tid = threadIdx.x;
#pragma unroll
    for (int l = 0; l < 3; ++l) {
        int j = tid + l * 256;  // 0..767 float4s: 48 rows x 16 f4
        int row = j >> 4, col = (j & 15) << 2;
        float4 t4 = *(const float4*)&src[(size_t)row * N_ + col];
        tile[row][col + 0] = t4.x;
        tile[row][col + 1] = t4.y;
        tile[row][col + 2] = t4.z;
        tile[row][col + 3] = t4.w;
    }
    __syncthreads();
    float* dst = out1 + ((size_t)(tb * HEADS_ + head) * N_ + n0) * DH_;
#pragma unroll
    for (int l = 0; l < 12; ++l) {
        int flat = tid + l * 256;  // 0..3071
        int nn = flat / DH_, dd = flat % DH_;
        dst[flat] = tile[dd][nn];
    }
}

// ---------------------------------------------------------------------------
// K6: out_pre = q * kv  (broadcast over n), float4
// ---------------------------------------------------------------------------
__global__ __launch_bounds__(256) void qkv_kernel(const float* __restrict__ q,
                                                  const float* __restrict__ kvsp,
                                                  float* __restrict__ outp) {
    size_t idx = ((size_t)blockIdx.x * 256 + threadIdx.x) << 2;  // over TBCN_
    int tb = (int)(idx / CN_);
    int c = (int)((idx % CN_) >> 10);
    float kvv = kvsp[tb * C_ + c];
    float4 qv = *(const float4*)&q[idx];
    float4 o;
    o.x = qv.x * kvv; o.y = qv.y * kvv; o.z = qv.z * kvv; o.w = qv.w * kvv;
    *(float4*)&outp[idx] = o;
}

// ---------------------------------------------------------------------------
extern "C" void kernel_launch(void* const* d_in, const int* in_sizes, int n_in,
                              void* d_out, int out_size, void* d_ws, size_t ws_size,
                              hipStream_t stream) {
    (void)in_sizes; (void)n_in; (void)out_size; (void)ws_size;
    const float* x      = (const float*)d_in[0];
    const float* q_w    = (const float*)d_in[1];
    const float* q_g    = (const float*)d_in[2];
    const float* q_b    = (const float*)d_in[3];
    const float* q_m    = (const float*)d_in[4];
    const float* q_v    = (const float*)d_in[5];
    const float* k_w    = (const float*)d_in[6];
    const float* k_g    = (const float*)d_in[7];
    const float* k_b    = (const float*)d_in[8];
    const float* k_m    = (const float*)d_in[9];
    const float* k_v    = (const float*)d_in[10];
    const float* v_w    = (const float*)d_in[11];
    const float* v_g    = (const float*)d_in[12];
    const float* v_b    = (const float*)d_in[13];
    const float* v_m    = (const float*)d_in[14];
    const float* v_v    = (const float*)d_in[15];
    const float* proj_w = (const float*)d_in[16];
    const float* proj_b = (const float*)d_in[17];
    const float* p_g    = (const float*)d_in[18];
    const float* p_be   = (const float*)d_in[19];
    const float* p_m    = (const float*)d_in[20];
    const float* p_v    = (const float*)d_in[21];

    float* out0 = (float*)d_out;
    float* out1 = out0 + TBCN_;

    float* xs   = (float*)d_ws;          // also reused as out_pre later
    float* yq   = xs + TBCN_;
    float* yk   = yq + TBCN_;
    float* yv   = yk + TBCN_;
    float* kvsp = yv + TBCN_;            // T_*B_*C_ floats

    // 1) shortcut LIF
    lif_x_kernel<<<BCN_ / 256, 256, 0, stream>>>(x, xs);

    // 2) three branch GEMMs (raw conv1x1 outputs)
    dim3 gg(N_ / 64, C_ / 128, T_ * B_);
    gemm_kernel<<<gg, 256, 0, stream>>>(xs, q_w, yq, nullptr, nullptr, nullptr,
                                        nullptr, nullptr, nullptr);
    gemm_kernel<<<gg, 256, 0, stream>>>(xs, k_w, yk, nullptr, nullptr, nullptr,
                                        nullptr, nullptr, nullptr);
    gemm_kernel<<<gg, 256, 0, stream>>>(xs, v_w, yv, nullptr, nullptr, nullptr,
                                        nullptr, nullptr, nullptr);

    // 3) BN + LIF per branch (in-place -> binary spikes)
    branch_lif_kernel<<<BCN_ / 256, 256, 0, stream>>>(yq, q_g, q_b, q_m, q_v);
    branch_lif_kernel<<<BCN_ / 256, 256, 0, stream>>>(yk, k_g, k_b, k_m, k_v);
    branch_lif_kernel<<<BCN_ / 256, 256, 0, stream>>>(yv, v_g, v_b, v_m, v_v);

    // 4) kv = LIF(sum_n k*v, 0.5)  (exact)
    kv_kernel<<<B_ * C_, 256, 0, stream>>>(yk, yv, kvsp);

    // 5) output 1: v spikes in head layout
    transpose_v_kernel<<<dim3(N_ / 64, HEADS_, T_ * B_), 256, 0, stream>>>(yv, out1);

    // 6) out_pre = q * kv  (into xs buffer, no longer needed)
    qkv_kernel<<<TBCN_ / 1024, 256, 0, stream>>>(yq, kvsp, xs);

    // 7) proj GEMM + bias + BN + identity -> output 0
    gemm_kernel<<<gg, 256, 0, stream>>>(xs, proj_w, out0, proj_b, p_g, p_be,
                                        p_m, p_v, x);
}

// Round 2
// 620.285 us; speedup vs baseline: 2.3859x; 2.3859x over previous
//
#include <hip/hip_runtime.h>
#include <math.h>

#define T_ 4
#define B_ 16
#define C_ 384
#define N_ 1024
#define CN_ (C_ * N_)      // 393216
#define BCN_ (B_ * CN_)    // 6291456
#define TBCN_ (T_ * BCN_)  // 25165824
#define HEADS_ 8
#define DH_ 48
#define EPS_ 1e-5f
#define NW_ 12             // 384 bits -> 12 words per column
#define M3_ 1152           // 3*C_

// ---------------------------------------------------------------------------
// P1: Wt_qkv[c][br*384+m] = W_br[m][c]   (concat q,k,v, transposed)
// ---------------------------------------------------------------------------
__global__ __launch_bounds__(256) void prep_wt_qkv(
        const float* __restrict__ qw, const float* __restrict__ kw,
        const float* __restrict__ vw, float* __restrict__ Wt) {
    int idx = blockIdx.x * 256 + threadIdx.x;  // over 384*384
    int m = idx / C_, c = idx % C_;
    Wt[(size_t)c * M3_ + m]       = qw[idx];
    Wt[(size_t)c * M3_ + 384 + m] = kw[idx];
    Wt[(size_t)c * M3_ + 768 + m] = vw[idx];
}

__global__ __launch_bounds__(256) void prep_wt_proj(
        const float* __restrict__ pw, float* __restrict__ Wtp) {
    int idx = blockIdx.x * 256 + threadIdx.x;
    int m = idx / C_, c = idx % C_;
    Wtp[(size_t)c * C_ + m] = pw[idx];
}

// ---------------------------------------------------------------------------
// P2: per-m' BN constants for qkv branches (inv computed exactly as reference)
// ---------------------------------------------------------------------------
__global__ __launch_bounds__(256) void prep_bn(
        const float* __restrict__ qg, const float* __restrict__ qb,
        const float* __restrict__ qm, const float* __restrict__ qv,
        const float* __restrict__ kg, const float* __restrict__ kb,
        const float* __restrict__ km, const float* __restrict__ kv2,
        const float* __restrict__ vg, const float* __restrict__ vb,
        const float* __restrict__ vm, const float* __restrict__ vv,
        float* __restrict__ invA, float* __restrict__ muA, float* __restrict__ beA) {
    int i = blockIdx.x * 256 + threadIdx.x;
    if (i >= M3_) return;
    int br = i / C_, c = i % C_;
    const float *g, *bb, *mm, *va;
    if (br == 0)      { g = qg; bb = qb; mm = qm; va = qv; }
    else if (br == 1) { g = kg; bb = kb; mm = km; va = kv2; }
    else              { g = vg; bb = vb; mm = vm; va = vv; }
    invA[i] = g[c] / sqrtf(va[c] + EPS_);
    muA[i]  = mm[c];
    beA[i]  = bb[c];
}

// ---------------------------------------------------------------------------
// K1: shortcut LIF on x -> column bitmasks  mask_x[t][b][w][n]
// thread = (b, cw, n); loops cb (c within word) outer, t inner (v resets per c)
// ---------------------------------------------------------------------------
__global__ __launch_bounds__(256) void lif_x_mask(const float* __restrict__ x,
                                                  unsigned* __restrict__ mask_x) {
    int n  = blockIdx.x * 256 + threadIdx.x;
    int cw = blockIdx.y;   // 0..11
    int b  = blockIdx.z;   // 0..15
    unsigned wrd[T_] = {0u, 0u, 0u, 0u};
    const float* xb = x + (size_t)b * CN_ + (size_t)cw * 32 * N_ + n;
#pragma unroll 4
    for (int cb = 0; cb < 32; ++cb) {
        const float* xp = xb + (size_t)cb * N_;
        float v = 0.f;
#pragma unroll
        for (int t = 0; t < T_; ++t) {
            float xt = xp[(size_t)t * BCN_];
            v = v + (xt - v) * 0.5f;   // == v + (x - v)/2 exactly
            if (v >= 1.0f) { wrd[t] |= (1u << cb); v = 0.f; }
        }
    }
#pragma unroll
    for (int t = 0; t < T_; ++t)
        mask_x[((size_t)(t * B_ + b) * NW_ + cw) * N_ + n] = wrd[t];
}

// ---------------------------------------------------------------------------
// K3: fused sparse QKV GEMM + BN + LIF -> spike bitmasks for q,k,v
// wave per column (b,n); t-loop inside; per-lane state for 18 m' = lane+j*64.
// GEMM = sum of Wt rows for active c bits (exact fp32 adds, ascending c).
// ---------------------------------------------------------------------------
__global__ __launch_bounds__(256) void qkv_sparse(
        const unsigned* __restrict__ mask_x, const float* __restrict__ Wt,
        const float* __restrict__ invA, const float* __restrict__ muA,
        const float* __restrict__ beA,
        unsigned* __restrict__ mq, unsigned* __restrict__ mk,
        unsigned* __restrict__ mv) {
    const int lane = threadIdx.x & 63;
    const int col  = threadIdx.x >> 6;   // 0..3
    const int n = blockIdx.x * 4 + col;
    const int b = blockIdx.y;

    float inv[18], mu[18], be[18], vst[18];
#pragma unroll
    for (int j = 0; j < 18; ++j) {
        int m = lane + j * 64;
        inv[j] = invA[m]; mu[j] = muA[m]; be[j] = beA[m];
        vst[j] = 0.f;
    }

    for (int t = 0; t < T_; ++t) {
        float acc[18];
#pragma unroll
        for (int j = 0; j < 18; ++j) acc[j] = 0.f;
        const unsigned* mp = mask_x + (size_t)(t * B_ + b) * NW_ * N_ + n;
        for (int w = 0; w < NW_; ++w) {
            unsigned bits = mp[(size_t)w * N_];
            while (bits) {
                int cb = __builtin_ctz(bits);
                bits &= bits - 1;
                const float* wr = Wt + (size_t)(w * 32 + cb) * M3_ + lane;
#pragma unroll
                for (int j = 0; j < 18; ++j) acc[j] += wr[j * 64];
            }
        }
#pragma unroll
        for (int j = 0; j < 18; ++j) {
            float pre = (acc[j] - mu[j]) * inv[j] + be[j];   // BN, unfolded
            float v2 = vst[j] + (pre - vst[j]) * 0.5f;       // LIF charge
            bool s = (v2 >= 1.0f);
            vst[j] = s ? 0.f : v2;
            unsigned long long bal = __ballot(s);
            if (lane == 0) {
                int br = j / 6, wq = (j % 6) * 2;
                unsigned* dst = (br == 0 ? mq : (br == 1 ? mk : mv)) +
                                (size_t)(t * B_ + b) * NW_ * N_ + n;
                dst[(size_t)wq * N_]       = (unsigned)bal;
                dst[(size_t)(wq + 1) * N_] = (unsigned)(bal >> 32);
            }
        }
    }
}

// ---------------------------------------------------------------------------
// K4a: per (t,b,c) count = sum_n k&v  (popcount over AND of masks)
// thread = (w, n-chunk of 32 words); per-bit counts -> LDS atomic -> global
// ---------------------------------------------------------------------------
__global__ __launch_bounds__(384) void kv_count(const unsigned* __restrict__ mk,
                                                const unsigned* __restrict__ mv,
                                                int* __restrict__ cnt) {
    int tb = blockIdx.x;                // t*B_+b
    int w = threadIdx.x >> 5, chunk = threadIdx.x & 31;
    __shared__ int sc[C_];
    if (threadIdx.x < C_) sc[threadIdx.x] = 0;
    __syncthreads();
    const unsigned* kp = mk + ((size_t)tb * NW_ + w) * N_ + chunk * 32;
    const unsigned* vp = mv + ((size_t)tb * NW_ + w) * N_ + chunk * 32;
    int loc[32];
#pragma unroll
    for (int bit = 0; bit < 32; ++bit) loc[bit] = 0;
#pragma unroll
    for (int i = 0; i < 32; ++i) {
        unsigned a = kp[i] & vp[i];
#pragma unroll
        for (int bit = 0; bit < 32; ++bit) loc[bit] += (int)((a >> bit) & 1u);
    }
#pragma unroll
    for (int bit = 0; bit < 32; ++bit)
        if (loc[bit]) atomicAdd(&sc[w * 32 + bit], loc[bit]);
    __syncthreads();
    if (threadIdx.x < C_) cnt[(size_t)tb * C_ + threadIdx.x] = sc[threadIdx.x];
}

// ---------------------------------------------------------------------------
// K4b: LIF over t on counts (v_th=0.5, exact dyadic arithmetic) -> kv words
// block per b, thread = c (384); ballot -> kvw[t][b][12]
// ---------------------------------------------------------------------------
__global__ __launch_bounds__(384) void kv_lif(const int* __restrict__ cnt,
                                              unsigned* __restrict__ kvw) {
    int b = blockIdx.x, c = threadIdx.x;
    float u = 0.f;
    for (int t = 0; t < T_; ++t) {
        float ct = (float)cnt[(size_t)(t * B_ + b) * C_ + c];
        u = u + (ct - u) * 0.5f;
        bool s = (u >= 0.5f);
        u = s ? 0.f : u;
        unsigned long long bal = __ballot(s);
        if ((c & 63) == 0) {
            int wv = c >> 6;   // wave 0..5 -> words 2wv, 2wv+1
            kvw[(size_t)(t * B_ + b) * NW_ + wv * 2]     = (unsigned)bal;
            kvw[(size_t)(t * B_ + b) * NW_ + wv * 2 + 1] = (unsigned)(bal >> 32);
        }
    }
}

// ---------------------------------------------------------------------------
// K5: output 1 — v spikes to head layout [tb][h][n][dd], from mask_v
// ---------------------------------------------------------------------------
__global__ __launch_bounds__(256) void v_to_out1(const unsigned* __restrict__ mv,
                                                 float* __restrict__ out1) {
    int tb = blockIdx.y;
    int n0 = blockIdx.x * 128;
    __shared__ unsigned ws_[NW_][128];
    for (int i = threadIdx.x; i < NW_ * 128; i += 256) {
        int w = i >> 7, nn = i & 127;
        ws_[w][nn] = mv[((size_t)tb * NW_ + w) * N_ + n0 + nn];
    }
    __syncthreads();
    float* dst = out1 + (size_t)tb * HEADS_ * N_ * DH_;
    for (int h = 0; h < HEADS_; ++h) {
        float* dh = dst + ((size_t)h * N_ + n0) * DH_;
#pragma unroll
        for (int l = 0; l < 24; ++l) {
            int flat = l * 256 + threadIdx.x;       // 0..6143 (128n x 48dd)
            int nn = flat / DH_, dd = flat - nn * DH_;
            int c = h * DH_ + dd;
            unsigned wd = ws_[c >> 5][nn];
            dh[flat] = (float)((wd >> (c & 31)) & 1u);
        }
    }
}

// ---------------------------------------------------------------------------
// K6: proj sparse GEMM (active = qmask & kv) + bias + BN + identity -> out0
// block per (tb, n-tile 64, m-half 192): LDS acc[192][65], then coalesced write
// ---------------------------------------------------------------------------
__global__ __launch_bounds__(256) void proj_out0(
        const unsigned* __restrict__ mq, const unsigned* __restrict__ kvw,
        const float* __restrict__ Wtp, const float* __restrict__ pb,
        const float* __restrict__ pg, const float* __restrict__ pbe,
        const float* __restrict__ pm, const float* __restrict__ pv,
        const float* __restrict__ x, float* __restrict__ out0) {
    int tb = blockIdx.y;
    int n0 = blockIdx.x * 64;
    int m0 = blockIdx.z * 192;
    __shared__ float acc[192][65];
    for (int i = threadIdx.x; i < 192 * 65; i += 256) ((float*)acc)[i] = 0.f;
    __syncthreads();
    const int lane = threadIdx.x & 63, wv = threadIdx.x >> 6;
    const unsigned* kvp = kvw + (size_t)tb * NW_;
    for (int ci = 0; ci < 16; ++ci) {
        int coln = wv * 16 + ci;
        const unsigned* mp = mq + (size_t)tb * NW_ * N_ + n0 + coln;
        for (int w = 0; w < NW_; ++w) {
            unsigned bits = mp[(size_t)w * N_] & kvp[w];
            while (bits) {
                int cb = __builtin_ctz(bits);
                bits &= bits - 1;
                const float* wr = Wtp + (size_t)(w * 32 + cb) * C_ + m0 + lane;
#pragma unroll
                for (int j = 0; j < 3; ++j)
                    acc[lane + j * 64][coln] += wr[j * 64];
            }
        }
    }
    __syncthreads();
    const float* xb = x + (size_t)tb * CN_ + (size_t)m0 * N_ + n0;
    float* ob = out0 + (size_t)tb * CN_ + (size_t)m0 * N_ + n0;
    for (int mi = 0; mi < 48; ++mi) {
        int ml = mi * 4 + wv;            // 0..191 local
        int m = m0 + ml;                 // global channel
        float inv = pg[m] / sqrtf(pv[m] + EPS_);
        float cst = (pb[m] - pm[m]) * inv + pbe[m];
        float a = acc[ml][lane];
        ob[(size_t)ml * N_ + lane] = a * inv + cst + xb[(size_t)ml * N_ + lane];
    }
}

// ---------------------------------------------------------------------------
extern "C" void kernel_launch(void* const* d_in, const int* in_sizes, int n_in,
                              void* d_out, int out_size, void* d_ws, size_t ws_size,
                              hipStream_t stream) {
    (void)in_sizes; (void)n_in; (void)out_size; (void)ws_size;
    const float* x      = (const float*)d_in[0];
    const float* q_w    = (const float*)d_in[1];
    const float* q_g    = (const float*)d_in[2];
    const float* q_b    = (const float*)d_in[3];
    const float* q_m    = (const float*)d_in[4];
    const float* q_v    = (const float*)d_in[5];
    const float* k_w    = (const float*)d_in[6];
    const float* k_g    = (const float*)d_in[7];
    const float* k_b    = (const float*)d_in[8];
    const float* k_m    = (const float*)d_in[9];
    const float* k_v    = (const float*)d_in[10];
    const float* v_w    = (const float*)d_in[11];
    const float* v_g    = (const float*)d_in[12];
    const float* v_b    = (const float*)d_in[13];
    const float* v_m    = (const float*)d_in[14];
    const float* v_v    = (const float*)d_in[15];
    const float* proj_w = (const float*)d_in[16];
    const float* proj_b = (const float*)d_in[17];
    const float* p_g    = (const float*)d_in[18];
    const float* p_be   = (const float*)d_in[19];
    const float* p_m    = (const float*)d_in[20];
    const float* p_v    = (const float*)d_in[21];

    float* out0 = (float*)d_out;
    float* out1 = out0 + TBCN_;

    char* p = (char*)d_ws;
    float* Wt_qkv  = (float*)p;    p += (size_t)C_ * M3_ * 4;   // 1.77 MB
    float* Wt_proj = (float*)p;    p += (size_t)C_ * C_ * 4;    // 0.59 MB
    float* invA    = (float*)p;    p += M3_ * 4;
    float* muA     = (float*)p;    p += M3_ * 4;
    float* beA     = (float*)p;    p += M3_ * 4;
    unsigned* mask_x = (unsigned*)p; p += (size_t)T_ * B_ * NW_ * N_ * 4;
    unsigned* mask_q = (unsigned*)p; p += (size_t)T_ * B_ * NW_ * N_ * 4;
    unsigned* mask_k = (unsigned*)p; p += (size_t)T_ * B_ * NW_ * N_ * 4;
    unsigned* mask_v = (unsigned*)p; p += (size_t)T_ * B_ * NW_ * N_ * 4;
    int* cnt       = (int*)p;      p += (size_t)T_ * B_ * C_ * 4;
    unsigned* kvw  = (unsigned*)p; p += (size_t)T_ * B_ * NW_ * 4;

    // prep (weights/BN constants)
    prep_wt_qkv<<<(C_ * C_) / 256, 256, 0, stream>>>(q_w, k_w, v_w, Wt_qkv);
    prep_wt_proj<<<(C_ * C_) / 256, 256, 0, stream>>>(proj_w, Wt_proj);
    prep_bn<<<(M3_ + 255) / 256, 256, 0, stream>>>(q_g, q_b, q_m, q_v,
                                                   k_g, k_b, k_m, k_v,
                                                   v_g, v_b, v_m, v_v,
                                                   invA, muA, beA);

    // 1) shortcut LIF -> xs bitmasks
    lif_x_mask<<<dim3(N_ / 256, NW_, B_), 256, 0, stream>>>(x, mask_x);

    // 2) fused sparse QKV conv + BN + LIF -> q/k/v bitmasks
    qkv_sparse<<<dim3(N_ / 4, B_), 256, 0, stream>>>(mask_x, Wt_qkv,
                                                     invA, muA, beA,
                                                     mask_q, mask_k, mask_v);

    // 3) kv counts + LIF (exact integer path)
    kv_count<<<T_ * B_, 384, 0, stream>>>(mask_k, mask_v, cnt);
    kv_lif<<<B_, 384, 0, stream>>>(cnt, kvw);

    // 4) output 1: v spikes in head layout
    v_to_out1<<<dim3(N_ / 128, T_ * B_), 256, 0, stream>>>(mask_v, out1);

    // 5) proj sparse GEMM + bias + BN + identity -> output 0
    proj_out0<<<dim3(N_ / 64, T_ * B_, 2), 256, 0, stream>>>(
        mask_q, kvw, Wt_proj, proj_b, p_g, p_be, p_m, p_v, x, out0);
}